// Round 6
// baseline (279.504 us; speedup 1.0000x reference)
//
#include <hip/hip_runtime.h>

// ---------------------------------------------------------------------------
// CriticWithGNN. Only edges with receiver < n_agents (~2%) matter. All dense
// layers run on MFMA with split-precision bf16 (hi=RNE(f), lo=RNE(f-hi);
// A*W ~= Alo*Whi + Ahi*Wlo + Ahi*Whi, rel err ~2^-18). Activations live in
// LDS as PRE-SPLIT bf16 hi/lo planes -> inner loop is ds_read_b128 + MFMA,
// no per-k float->bf16 conversion. Weights pre-packed into B-frag layout.
// R6: node pipeline moved to MFMA (was fp32 latency-bound at 63us, VALU 10%).
// ---------------------------------------------------------------------------

typedef __attribute__((ext_vector_type(8))) short short8;
typedef __attribute__((ext_vector_type(4))) float floatx4;
union Frag8 { short8 s; uint u[4]; };

#define RSU 132          // plane row stride in uints (2 bf16/uint), K<=256 +pad
#define RSS 264          // same, in ushorts

// ---- bf16 RNE split helpers ----
__device__ __forceinline__ uint f2bf(float f) {
    uint u = __float_as_uint(f);
    return (u + 0x7FFFu + ((u >> 16) & 1u)) >> 16;
}
__device__ __forceinline__ float bf2f(uint h) { return __uint_as_float(h << 16); }
// pack two elements: returns hi pair {bf16(f0)|bf16(f1)<<16}, sets lo pair
__device__ __forceinline__ uint split2(float f0, float f1, uint& lo) {
    uint h0 = f2bf(f0), h1 = f2bf(f1);
    uint l0 = f2bf(f0 - bf2f(h0)), l1 = f2bf(f1 - bf2f(h1));
    lo = l0 | (l1 << 16);
    return h0 | (h1 << 16);
}

// ---- packed-weight table (order: Wm1,Wm2,Wm3,Wa1,Wa2,Wa3,Wu1,Wu2,Wu3,Wact,Wh1,Wh2)
constexpr int PK_NIN[12]  = {128,256,256, 128,128,128, 192,256,256, 32, 256,256};
constexpr int PK_KREAL[12]= {128,256,256, 128,128,128, 192,256,256, 16, 256,256};
constexpr int PK_NOUT[12] = {256,256,128, 128,128,128, 256,256,128, 128,256,256};
constexpr int pk_entries(int m) { return (PK_NIN[m]/32)*(PK_NOUT[m]/16)*64; } // uint4/plane
constexpr int pk_cum(int m) { int s = 0; for (int i = 0; i < m; ++i) s += pk_entries(i); return s; }
constexpr int PK_TOTAL = pk_cum(12);                 // 57856 uint4 per plane-set
constexpr int pk_off_hi(int m) { return 2*pk_cum(m); }
constexpr int pk_off_lo(int m) { return 2*pk_cum(m) + pk_entries(m); }
// pack bytes = 2*PK_TOTAL*16 = 1,851,392

struct PackPtrs { const float* W[12]; };

// Pack all weights into MFMA B-frag layout (hi+lo planes). Also zeroes
// counter and aggr (replaces the memset dispatch).
__global__ void pack_weights(PackPtrs P, uint4* pack,
                             int* counter, float* aggr, int aggrN) {
    int g = blockIdx.x * 256 + threadIdx.x;
    if (g == 0) *counter = 0;
    for (int i = g; i < aggrN; i += (int)gridDim.x * 256) aggr[i] = 0.f;
    if (g >= PK_TOTAL) return;
    int m = 0;
#pragma unroll
    for (int i = 1; i < 12; ++i) if (g >= pk_cum(i)) m = i;
    int local = g - pk_cum(m);
    const float* W = P.W[m];
    int NOUT = PK_NOUT[m], KREAL = PK_KREAL[m], NT = NOUT / 16;
    int lane = local & 63;
    int tmp  = local >> 6;
    int nt = tmp % NT, kb = tmp / NT;
    int n  = nt * 16 + (lane & 15);
    int k0 = kb * 32 + (lane >> 4) * 8;
    uint hi[4], lo[4];
#pragma unroll
    for (int p = 0; p < 4; ++p) {
        int ke = k0 + 2*p, ko = ke + 1;
        float f0 = (ke < KREAL) ? W[(size_t)ke * NOUT + n] : 0.f;
        float f1 = (ko < KREAL) ? W[(size_t)ko * NOUT + n] : 0.f;
        hi[p] = split2(f0, f1, lo[p]);
    }
    pack[pk_off_hi(m) + local] = make_uint4(hi[0], hi[1], hi[2], hi[3]);
    pack[pk_off_lo(m) + local] = make_uint4(lo[0], lo[1], lo[2], lo[3]);
}

// ---- edge compaction (wave-ballot) ----
#define FILT_CHUNK 4096
__global__ void filter_edges(const int* __restrict__ senders,
                             const int* __restrict__ receivers,
                             int E, int n_agents, int cap,
                             int* __restrict__ counter, int2* __restrict__ edges) {
    __shared__ int lcount;
    __shared__ int lbase;
    __shared__ int2 lbuf[FILT_CHUNK];
    const int t = (int)threadIdx.x;
    if (t == 0) lcount = 0;
    __syncthreads();
    int start = blockIdx.x * FILT_CHUNK;
    int end = min(start + FILT_CHUNK, E);
    for (int b0 = start; b0 < end; b0 += 256) {
        int idx = b0 + t;
        int r = -1, s = 0;
        bool pred = false;
        if (idx < end) {
            r = receivers[idx];
            pred = (r < n_agents);
            if (pred) s = senders[idx];
        }
        unsigned long long m = __ballot(pred);
        int lane = t & 63;
        int below = __popcll(m & ((1ull << lane) - 1));
        int cnt = __popcll(m);
        int wbase = 0;
        if (lane == 0 && cnt) wbase = atomicAdd(&lcount, cnt);
        wbase = __shfl(wbase, 0, 64);
        if (pred) lbuf[wbase + below] = make_int2(s, r);
    }
    __syncthreads();
    if (t == 0) lbase = atomicAdd(counter, lcount);
    __syncthreads();
    for (int i = t; i < lcount; i += 256) {
        int pos = lbase + i;
        if (pos < cap) edges[pos] = lbuf[i];
    }
}

// ---- MFMA dense layer over pre-split LDS planes --------------------------
// A: M 16-row tiles in hi/lo planes (uint, stride RSU). B: packed global.
// Epilogue modes: write split planes (relu / no-relu), atomic scatter (edge
// msg), or fused q-dot (node head). Internal barrier separates the read
// phase from in-place plane writes.
enum { EPI_PLANES = 0, EPI_PLANES_NORELU = 1, EPI_ATOMIC = 2, EPI_Q = 3 };

struct EpiArgs {
    const float* bias;
    ushort* dH; ushort* dL; int koff;            // planes modes
    float* aggr; const int* rL; int base; int count;  // atomic mode
    const float* Wq; float* qp;                  // q mode
};

template<int M, int NIN, int NOUT, int MODE, int OHI, int OLO>
__device__ __forceinline__ void mfma_dense(const uint* aH, const uint* aL,
                                           const uint4* __restrict__ pW,
                                           EpiArgs ea) {
    constexpr int KB = NIN / 32, NT = NOUT / 16, NTW = NT / 4;
    const int t = (int)threadIdx.x;
    const int wave = t >> 6, lane = t & 63, l15 = t & 15, quad = (t >> 4) & 3;

    floatx4 acc[M][NTW];
#pragma unroll
    for (int mt = 0; mt < M; ++mt)
#pragma unroll
        for (int i = 0; i < NTW; ++i) acc[mt][i] = (floatx4){0.f, 0.f, 0.f, 0.f};

#pragma unroll
    for (int kb = 0; kb < KB; ++kb) {
        Frag8 ah[M], al[M];
#pragma unroll
        for (int mt = 0; mt < M; ++mt) {
            int ro = (mt * 16 + l15) * RSU + kb * 16 + quad * 4;
            *(uint4*)ah[mt].u = *(const uint4*)(aH + ro);
            *(uint4*)al[mt].u = *(const uint4*)(aL + ro);
        }
#pragma unroll
        for (int i = 0; i < NTW; ++i) {
            int widx = (kb * NT + wave * NTW + i) * 64 + lane;
            Frag8 bh, bl;
            *(uint4*)bh.u = pW[OHI + widx];
            *(uint4*)bl.u = pW[OLO + widx];
#pragma unroll
            for (int mt = 0; mt < M; ++mt) {
                acc[mt][i] = __builtin_amdgcn_mfma_f32_16x16x32_bf16(al[mt].s, bh.s, acc[mt][i], 0, 0, 0);
                acc[mt][i] = __builtin_amdgcn_mfma_f32_16x16x32_bf16(ah[mt].s, bl.s, acc[mt][i], 0, 0, 0);
                acc[mt][i] = __builtin_amdgcn_mfma_f32_16x16x32_bf16(ah[mt].s, bh.s, acc[mt][i], 0, 0, 0);
            }
        }
    }
    __syncthreads();   // all plane reads done; in-place writes now safe

    if constexpr (MODE == EPI_Q) {
        float p[4] = {0.f, 0.f, 0.f, 0.f};
#pragma unroll
        for (int i = 0; i < NTW; ++i) {
            int n = (wave * NTW + i) * 16 + l15;
            float bias = ea.bias[n], wq = ea.Wq[n];
#pragma unroll
            for (int r = 0; r < 4; ++r)
                p[r] += fmaxf(acc[0][i][r] + bias, 0.f) * wq;
        }
#pragma unroll
        for (int r = 0; r < 4; ++r) {
            p[r] += __shfl_xor(p[r], 1, 64);
            p[r] += __shfl_xor(p[r], 2, 64);
            p[r] += __shfl_xor(p[r], 4, 64);
            p[r] += __shfl_xor(p[r], 8, 64);
            if (l15 == 0) ea.qp[wave * 16 + quad * 4 + r] = p[r];
        }
    } else if constexpr (MODE == EPI_ATOMIC) {
#pragma unroll
        for (int i = 0; i < NTW; ++i) {
            int n = (wave * NTW + i) * 16 + l15;
            float bias = ea.bias[n];
#pragma unroll
            for (int mt = 0; mt < M; ++mt)
#pragma unroll
                for (int r = 0; r < 4; ++r) {
                    int e = mt * 16 + quad * 4 + r;
                    if (ea.base + e < ea.count)
                        atomicAdd(&ea.aggr[(size_t)ea.rL[e] * 128 + n],
                                  acc[mt][i][r] + bias);
                }
        }
    } else {
#pragma unroll
        for (int i = 0; i < NTW; ++i) {
            int n = (wave * NTW + i) * 16 + l15;
            float bias = ea.bias[n];
#pragma unroll
            for (int mt = 0; mt < M; ++mt)
#pragma unroll
                for (int r = 0; r < 4; ++r) {
                    int row = mt * 16 + quad * 4 + r;
                    float v = acc[mt][i][r] + bias;
                    if constexpr (MODE == EPI_PLANES) v = fmaxf(v, 0.f);
                    uint h = f2bf(v);
                    uint l = f2bf(v - bf2f(h));
                    ea.dH[row * RSS + ea.koff + n] = (ushort)h;
                    ea.dL[row * RSS + ea.koff + n] = (ushort)l;
                }
        }
    }
}

// ---- edge message MLP: 32-edge tiles, atomic scatter into aggr -----------
__global__ __launch_bounds__(256, 2)
void edge_mlp(const float* __restrict__ x, const int2* __restrict__ edges,
              const int* __restrict__ counter, int cap, float* __restrict__ aggr,
              const uint4* __restrict__ pack,
              const float* __restrict__ bm1, const float* __restrict__ bm2,
              const float* __restrict__ bm3) {
    __shared__ uint plH[32 * RSU];
    __shared__ uint plL[32 * RSU];
    __shared__ int sS[32], sR[32];
    ushort* sH = (ushort*)plH; ushort* sLo = (ushort*)plL;
    const int count = min(counter[0], cap);
    const int ntiles = (count + 31) >> 5;
    const int t = (int)threadIdx.x;
    EpiArgs ea = {};
    for (int tile = (int)blockIdx.x; tile < ntiles; tile += (int)gridDim.x) {
        const int base = tile * 32;
        if (t < 32) {
            int eg = base + t;
            int2 ed = (eg < count) ? edges[eg] : make_int2(0, -1);
            sS[t] = ed.x; sR[t] = ed.y;
        }
        __syncthreads();
        // gather h0 = [x[s] | x[r]] -> split planes k0..127 (float2 loads)
#pragma unroll
        for (int i = 0; i < 8; ++i) {
            int idx = t + i * 256;               // 2048 uint slots
            int e = idx >> 6, ku = idx & 63, kp = ku * 2;
            int node = (kp < 64) ? sS[e] : sR[e];
            float2 f = make_float2(0.f, 0.f);
            if (sR[e] >= 0) f = *(const float2*)(x + (size_t)node * 64 + (kp & 63));
            uint lo, hi = split2(f.x, f.y, lo);
            plH[e * RSU + ku] = hi; plL[e * RSU + ku] = lo;
        }
        __syncthreads();
        ea.bias = bm1; ea.dH = sH; ea.dL = sLo; ea.koff = 0;
        mfma_dense<2, 128, 256, EPI_PLANES, pk_off_hi(0), pk_off_lo(0)>(plH, plL, pack, ea);
        __syncthreads();
        ea.bias = bm2;
        mfma_dense<2, 256, 256, EPI_PLANES, pk_off_hi(1), pk_off_lo(1)>(plH, plL, pack, ea);
        __syncthreads();
        ea.bias = bm3; ea.aggr = aggr; ea.rL = sR; ea.base = base; ea.count = count;
        mfma_dense<2, 256, 128, EPI_ATOMIC, pk_off_hi(2), pk_off_lo(2)>(plH, plL, pack, ea);
        __syncthreads();   // protect sS/sR + planes before next tile
    }
}

// ---- action projection: A from global (K=16 padded to 32), write planes --
__device__ __forceinline__ void act_layer(const float* __restrict__ actions,
                                          int base, int n_agents,
                                          const uint4* __restrict__ pW,
                                          const float* __restrict__ bias,
                                          ushort* dH, ushort* dL, int koff) {
    const int t = (int)threadIdx.x;
    const int wave = t >> 6, lane = t & 63, l15 = t & 15, quad = (t >> 4) & 3;
    Frag8 ah, al;
#pragma unroll
    for (int p = 0; p < 4; ++p) { ah.u[p] = 0; al.u[p] = 0; }
    if (quad < 2 && base + l15 < n_agents) {
        const float* ap = actions + (size_t)(base + l15) * 16 + quad * 8;
        float4 f0 = *(const float4*)ap;
        float4 f1 = *(const float4*)(ap + 4);
        ah.u[0] = split2(f0.x, f0.y, al.u[0]);
        ah.u[1] = split2(f0.z, f0.w, al.u[1]);
        ah.u[2] = split2(f1.x, f1.y, al.u[2]);
        ah.u[3] = split2(f1.z, f1.w, al.u[3]);
    }
    floatx4 acc[2];
    acc[0] = (floatx4){0.f, 0.f, 0.f, 0.f};
    acc[1] = (floatx4){0.f, 0.f, 0.f, 0.f};
#pragma unroll
    for (int i = 0; i < 2; ++i) {
        int widx = (wave * 2 + i) * 64 + lane;   // KB=1, NT=8
        Frag8 bh, bl;
        *(uint4*)bh.u = pW[pk_off_hi(9) + widx];
        *(uint4*)bl.u = pW[pk_off_lo(9) + widx];
        acc[i] = __builtin_amdgcn_mfma_f32_16x16x32_bf16(al.s, bh.s, acc[i], 0, 0, 0);
        acc[i] = __builtin_amdgcn_mfma_f32_16x16x32_bf16(ah.s, bl.s, acc[i], 0, 0, 0);
        acc[i] = __builtin_amdgcn_mfma_f32_16x16x32_bf16(ah.s, bh.s, acc[i], 0, 0, 0);
    }
#pragma unroll
    for (int i = 0; i < 2; ++i) {
        int n = (wave * 2 + i) * 16 + l15;
        float b = bias[n];
#pragma unroll
        for (int r = 0; r < 4; ++r) {
            int row = quad * 4 + r;
            float v = fmaxf(acc[i][r] + b, 0.f);
            uint h = f2bf(v);
            uint l = f2bf(v - bf2f(h));
            dH[row * RSS + koff + n] = (ushort)h;
            dL[row * RSS + koff + n] = (ushort)l;
        }
    }
}

// ---- fused node pipeline: aggMLP -> updateMLP -> actProj -> head -> q ----
// 16 nodes per block, 64 blocks. All layers MFMA over in-place planes.
__global__ __launch_bounds__(256, 1)
void node_update(const float* __restrict__ x, const float* __restrict__ actions,
                 const float* __restrict__ aggr, int n_agents,
                 const uint4* __restrict__ pack,
                 const float* __restrict__ ba1, const float* __restrict__ ba2,
                 const float* __restrict__ ba3,
                 const float* __restrict__ bu1, const float* __restrict__ bu2,
                 const float* __restrict__ bu3,
                 const float* __restrict__ bact,
                 const float* __restrict__ bh1, const float* __restrict__ bh2,
                 const float* __restrict__ Wq,  const float* __restrict__ bq,
                 float* __restrict__ out) {
    __shared__ uint plH[16 * RSU];
    __shared__ uint plL[16 * RSU];
    __shared__ float qp[64];
    ushort* sH = (ushort*)plH; ushort* sLo = (ushort*)plL;
    const int t = (int)threadIdx.x;
    const int base = (int)blockIdx.x * 16;
    EpiArgs ea = {};

    // stage aggr rows -> planes k0..127
#pragma unroll
    for (int i = 0; i < 4; ++i) {
        int idx = t + i * 256;                   // 1024 uint slots
        int e = idx >> 6, ku = idx & 63;
        float2 f = make_float2(0.f, 0.f);
        if (base + e < n_agents) f = *(const float2*)(aggr + (size_t)(base + e) * 128 + ku * 2);
        uint lo, hi = split2(f.x, f.y, lo);
        plH[e * RSU + ku] = hi; plL[e * RSU + ku] = lo;
    }
    __syncthreads();
    ea.dH = sH; ea.dL = sLo;
    // agg MLP
    ea.bias = ba1; ea.koff = 0;
    mfma_dense<1, 128, 128, EPI_PLANES, pk_off_hi(3), pk_off_lo(3)>(plH, plL, pack, ea);
    __syncthreads();
    ea.bias = ba2;
    mfma_dense<1, 128, 128, EPI_PLANES, pk_off_hi(4), pk_off_lo(4)>(plH, plL, pack, ea);
    __syncthreads();
    ea.bias = ba3; ea.koff = 64;   // a -> k 64..191 of u0
    mfma_dense<1, 128, 128, EPI_PLANES_NORELU, pk_off_hi(5), pk_off_lo(5)>(plH, plL, pack, ea);
    // stage x -> k 0..63 (same post-read phase as a3's epilogue: safe)
#pragma unroll
    for (int i = 0; i < 2; ++i) {
        int idx = t + i * 256;                   // 512 uint slots
        int e = idx >> 5, ku = idx & 31;
        float2 f = make_float2(0.f, 0.f);
        if (base + e < n_agents) f = *(const float2*)(x + (size_t)(base + e) * 64 + ku * 2);
        uint lo, hi = split2(f.x, f.y, lo);
        plH[e * RSU + ku] = hi; plL[e * RSU + ku] = lo;
    }
    __syncthreads();
    // update MLP
    ea.bias = bu1; ea.koff = 0;
    mfma_dense<1, 192, 256, EPI_PLANES, pk_off_hi(6), pk_off_lo(6)>(plH, plL, pack, ea);
    __syncthreads();
    ea.bias = bu2;
    mfma_dense<1, 256, 256, EPI_PLANES, pk_off_hi(7), pk_off_lo(7)>(plH, plL, pack, ea);
    __syncthreads();
    ea.bias = bu3; ea.koff = 0;    // feats -> k 0..127 of z
    mfma_dense<1, 256, 128, EPI_PLANES_NORELU, pk_off_hi(8), pk_off_lo(8)>(plH, plL, pack, ea);
    // ap = relu(actions @ Wact) -> k 128..255 of z (A from global, no LDS dep)
    act_layer(actions, base, n_agents, pack, bact, sH, sLo, 128);
    __syncthreads();
    // head
    ea.bias = bh1; ea.koff = 0;
    mfma_dense<1, 256, 256, EPI_PLANES, pk_off_hi(10), pk_off_lo(10)>(plH, plL, pack, ea);
    __syncthreads();
    ea.bias = bh2; ea.Wq = Wq; ea.qp = qp;
    mfma_dense<1, 256, 256, EPI_Q, pk_off_hi(11), pk_off_lo(11)>(plH, plL, pack, ea);
    __syncthreads();
    if (t < 16 && base + t < n_agents)
        out[base + t] = qp[t] + qp[16 + t] + qp[32 + t] + qp[48 + t] + bq[0];
}

extern "C" void kernel_launch(void* const* d_in, const int* in_sizes, int n_in,
                              void* d_out, int out_size, void* d_ws, size_t ws_size,
                              hipStream_t stream) {
    const float* x        = (const float*)d_in[0];
    const float* actions  = (const float*)d_in[1];
    const int*   senders  = (const int*)d_in[2];
    const int*   receivers= (const int*)d_in[3];
    const float* Wm1 = (const float*)d_in[5],  *bm1 = (const float*)d_in[6];
    const float* Wm2 = (const float*)d_in[7],  *bm2 = (const float*)d_in[8];
    const float* Wm3 = (const float*)d_in[9],  *bm3 = (const float*)d_in[10];
    const float* Wa1 = (const float*)d_in[11], *ba1 = (const float*)d_in[12];
    const float* Wa2 = (const float*)d_in[13], *ba2 = (const float*)d_in[14];
    const float* Wa3 = (const float*)d_in[15], *ba3 = (const float*)d_in[16];
    const float* Wu1 = (const float*)d_in[17], *bu1 = (const float*)d_in[18];
    const float* Wu2 = (const float*)d_in[19], *bu2 = (const float*)d_in[20];
    const float* Wu3 = (const float*)d_in[21], *bu3 = (const float*)d_in[22];
    const float* Wact= (const float*)d_in[23], *bact= (const float*)d_in[24];
    const float* Wh1 = (const float*)d_in[25], *bh1 = (const float*)d_in[26];
    const float* Wh2 = (const float*)d_in[27], *bh2 = (const float*)d_in[28];
    const float* Wq  = (const float*)d_in[29], *bq  = (const float*)d_in[30];

    const int E = in_sizes[2];
    const int n_agents = out_size;

    // ws: [0,4) counter | [1024, +512K) aggr | packed W (1.85MB) | edges
    char* ws = (char*)d_ws;
    int*   counter = (int*)ws;
    float* aggr    = (float*)(ws + 1024);
    const size_t packOff = 1024 + (size_t)n_agents * 128 * sizeof(float);
    uint4* pack    = (uint4*)(ws + packOff);
    const size_t packBytes = (size_t)2 * PK_TOTAL * 16;
    const size_t edgeOff = packOff + packBytes;
    int2*  edges   = (int2*)(ws + edgeOff);
    int cap = (int)((ws_size > edgeOff) ? (ws_size - edgeOff) / sizeof(int2) : 0);
    if (cap > E) cap = E;

    PackPtrs P;
    P.W[0] = Wm1; P.W[1] = Wm2; P.W[2] = Wm3;
    P.W[3] = Wa1; P.W[4] = Wa2; P.W[5] = Wa3;
    P.W[6] = Wu1; P.W[7] = Wu2; P.W[8] = Wu3;
    P.W[9] = Wact; P.W[10] = Wh1; P.W[11] = Wh2;
    pack_weights<<<(PK_TOTAL + 255) / 256, 256, 0, stream>>>(
        P, pack, counter, aggr, n_agents * 128);

    filter_edges<<<(E + FILT_CHUNK - 1) / FILT_CHUNK, 256, 0, stream>>>(
        senders, receivers, E, n_agents, cap, counter, edges);

    edge_mlp<<<512, 256, 0, stream>>>(x, edges, counter, cap, aggr, pack,
                                      bm1, bm2, bm3);

    node_update<<<(n_agents + 15) / 16, 256, 0, stream>>>(
        x, actions, aggr, n_agents, pack,
        ba1, ba2, ba3, bu1, bu2, bu3, bact, bh1, bh2, Wq, bq,
        (float*)d_out);
}

// Round 7
// 195.484 us; speedup vs baseline: 1.4298x; 1.4298x over previous
//
#include <hip/hip_runtime.h>
#include <hip/hip_bf16.h>

// ---------------------------------------------------------------------------
// CriticWithGNN. Only edges with receiver < n_agents (~2%) matter (output is
// q[:n_agents]). Dense layers on MFMA with split-precision bf16:
// A*W ~= Alo*Whi + Ahi*Wlo + Ahi*Whi  (rel err ~2^-17, fp32-grade).
// R7: revert edge_mlp to the proven R5 structure (R6's plane/EpiArgs version
// generated ~300MB of scratch traffic); node_update now MFMA in R5 style.
// ---------------------------------------------------------------------------

#define STRIDE 260   // fp32 LDS row stride in words

typedef __attribute__((ext_vector_type(8))) short short8;
typedef __attribute__((ext_vector_type(4))) float floatx4;
union Frag8 { short8 s; uint u[4]; };

// hi = truncate-to-bf16 (mask), lo = RNE-bf16(f - hi)  [R5-proven, no spill]
__device__ __forceinline__ void cvt_hi_lo(const float4 f0, const float4 f1,
                                          Frag8& hi, Frag8& lo) {
    uint U[8] = { __float_as_uint(f0.x), __float_as_uint(f0.y),
                  __float_as_uint(f0.z), __float_as_uint(f0.w),
                  __float_as_uint(f1.x), __float_as_uint(f1.y),
                  __float_as_uint(f1.z), __float_as_uint(f1.w) };
    float F[8] = { f0.x, f0.y, f0.z, f0.w, f1.x, f1.y, f1.z, f1.w };
#pragma unroll
    for (int p = 0; p < 4; ++p) {
        uint a = U[2*p], b = U[2*p+1];
        hi.u[p] = (a >> 16) | (b & 0xFFFF0000u);
        float l0 = F[2*p]   - __uint_as_float(a & 0xFFFF0000u);
        float l1 = F[2*p+1] - __uint_as_float(b & 0xFFFF0000u);
        __hip_bfloat162 pl = __float22bfloat162_rn(make_float2(l0, l1));
        union { __hip_bfloat162 h; uint v; } cvt; cvt.h = pl;
        lo.u[p] = cvt.v;
    }
}

// ---- bf16 RNE split (weight packing) ----
__device__ __forceinline__ uint f2bf(float f) {
    uint u = __float_as_uint(f);
    return (u + 0x7FFFu + ((u >> 16) & 1u)) >> 16;
}
__device__ __forceinline__ float bf2f(uint h) { return __uint_as_float(h << 16); }
__device__ __forceinline__ uint split2(float f0, float f1, uint& lo) {
    uint h0 = f2bf(f0), h1 = f2bf(f1);
    uint l0 = f2bf(f0 - bf2f(h0)), l1 = f2bf(f1 - bf2f(h1));
    lo = l0 | (l1 << 16);
    return h0 | (h1 << 16);
}

// ---- packed-weight table (Wm1,Wm2,Wm3,Wa1,Wa2,Wa3,Wu1,Wu2,Wu3,Wh1,Wh2) ----
constexpr int PK_NIN[11]  = {128,256,256, 128,128,128, 192,256,256, 256,256};
constexpr int PK_NOUT[11] = {256,256,128, 128,128,128, 256,256,128, 256,256};
constexpr int pk_entries(int m) { return (PK_NIN[m]/32)*(PK_NOUT[m]/16)*64; } // uint4/plane
constexpr int pk_cum(int m) { int s = 0; for (int i = 0; i < m; ++i) s += pk_entries(i); return s; }
constexpr int PK_TOTAL = pk_cum(11);
constexpr int pk_off_hi(int m) { return 2*pk_cum(m); }
constexpr int pk_off_lo(int m) { return 2*pk_cum(m) + pk_entries(m); }

struct PackPtrs { const float* W[11]; };

#define FILT_CHUNK 4096

// Merged dispatch: blocks [0,FB) compact edges (wave-ballot filter);
// blocks [FB, FB+PB) pack weights into MFMA B-frag hi/lo planes.
// counter must be pre-zeroed (memset node) since filter uses atomicAdd.
__global__ void pack_and_filter(PackPtrs P, uint4* __restrict__ pack,
                                const int* __restrict__ senders,
                                const int* __restrict__ receivers,
                                int E, int n_agents, int cap,
                                int* __restrict__ counter,
                                int2* __restrict__ edges, int FB) {
    __shared__ int lcount;
    __shared__ int lbase;
    __shared__ int2 lbuf[FILT_CHUNK];
    const int t = (int)threadIdx.x;
    if ((int)blockIdx.x < FB) {
        if (t == 0) lcount = 0;
        __syncthreads();
        int start = blockIdx.x * FILT_CHUNK;
        int end = min(start + FILT_CHUNK, E);
        for (int b0 = start; b0 < end; b0 += 256) {
            int idx = b0 + t;
            int r = -1, s = 0;
            bool pred = false;
            if (idx < end) {
                r = receivers[idx];
                pred = (r < n_agents);
                if (pred) s = senders[idx];
            }
            unsigned long long m = __ballot(pred);
            int lane = t & 63;
            int below = __popcll(m & ((1ull << lane) - 1));
            int cnt = __popcll(m);
            int wbase = 0;
            if (lane == 0 && cnt) wbase = atomicAdd(&lcount, cnt);
            wbase = __shfl(wbase, 0, 64);
            if (pred) lbuf[wbase + below] = make_int2(s, r);
        }
        __syncthreads();
        if (t == 0) lbase = atomicAdd(counter, lcount);
        __syncthreads();
        for (int i = t; i < lcount; i += 256) {
            int pos = lbase + i;
            if (pos < cap) edges[pos] = lbuf[i];
        }
        return;
    }
    int g = ((int)blockIdx.x - FB) * 256 + t;
    if (g >= PK_TOTAL) return;
    int m = 0;
#pragma unroll
    for (int i = 1; i < 11; ++i) if (g >= pk_cum(i)) m = i;
    int local = g - pk_cum(m);
    const float* W = P.W[m];
    int NOUT = PK_NOUT[m], NT = NOUT / 16;
    int lane = local & 63;
    int tmp  = local >> 6;
    int nt = tmp % NT, kb = tmp / NT;
    int n  = nt * 16 + (lane & 15);
    int k0 = kb * 32 + (lane >> 4) * 8;
    uint hi[4], lo[4];
#pragma unroll
    for (int p = 0; p < 4; ++p) {
        float f0 = W[(size_t)(k0 + 2*p)     * NOUT + n];
        float f1 = W[(size_t)(k0 + 2*p + 1) * NOUT + n];
        hi[p] = split2(f0, f1, lo[p]);
    }
    pack[pk_off_hi(m) + local] = make_uint4(hi[0], hi[1], hi[2], hi[3]);
    pack[pk_off_lo(m) + local] = make_uint4(lo[0], lo[1], lo[2], lo[3]);
}

// ------------- MFMA dense layer on a 32-row fp32 LDS tile (R5-proven) ------
template<int NIN, int NOUT, bool RELU>
__device__ __forceinline__ void mfma_layer(const float* in_lds, float* out_lds,
                                           const uint4* __restrict__ Whi,
                                           const uint4* __restrict__ Wlo,
                                           const float* __restrict__ b) {
    constexpr int KB  = NIN / 32;
    constexpr int NT  = NOUT / 16;
    constexpr int NTW = NT / 4;
    const int t    = (int)threadIdx.x;
    const int wave = t >> 6;
    const int l15  = t & 15;
    const int quad = (t >> 4) & 3;

    floatx4 acc[2][NTW];
#pragma unroll
    for (int mt = 0; mt < 2; ++mt)
#pragma unroll
        for (int i = 0; i < NTW; ++i) acc[mt][i] = (floatx4){0.f, 0.f, 0.f, 0.f};

#pragma unroll 2
    for (int kb = 0; kb < KB; ++kb) {
        Frag8 ahi[2], alo[2];
#pragma unroll
        for (int mt = 0; mt < 2; ++mt) {
            const float* src = in_lds + (mt * 16 + l15) * STRIDE + kb * 32 + quad * 8;
            float4 f0 = *(const float4*)src;
            float4 f1 = *(const float4*)(src + 4);
            cvt_hi_lo(f0, f1, ahi[mt], alo[mt]);
        }
#pragma unroll
        for (int i = 0; i < NTW; ++i) {
            int nt = wave * NTW + i;
            int widx = (kb * NT + nt) * 64 + (t & 63);
            Frag8 bhi, blo;
            *(uint4*)bhi.u = Whi[widx];
            *(uint4*)blo.u = Wlo[widx];
#pragma unroll
            for (int mt = 0; mt < 2; ++mt) {
                acc[mt][i] = __builtin_amdgcn_mfma_f32_16x16x32_bf16(alo[mt].s, bhi.s, acc[mt][i], 0, 0, 0);
                acc[mt][i] = __builtin_amdgcn_mfma_f32_16x16x32_bf16(ahi[mt].s, blo.s, acc[mt][i], 0, 0, 0);
                acc[mt][i] = __builtin_amdgcn_mfma_f32_16x16x32_bf16(ahi[mt].s, bhi.s, acc[mt][i], 0, 0, 0);
            }
        }
    }
#pragma unroll
    for (int i = 0; i < NTW; ++i) {
        int n = (wave * NTW + i) * 16 + l15;
        float bias = b[n];
#pragma unroll
        for (int mt = 0; mt < 2; ++mt) {
#pragma unroll
            for (int r = 0; r < 4; ++r) {
                float v = acc[mt][i][r] + bias;
                if (RELU) v = fmaxf(v, 0.f);
                out_lds[(mt * 16 + quad * 4 + r) * STRIDE + n] = v;
            }
        }
    }
}

// Single 16-row tile variant with output column offset (node pipeline).
template<int NIN, int NOUT, bool RELU, int OOFF>
__device__ __forceinline__ void mfma_layer16(const float* in_lds, float* out_lds,
                                             const uint4* __restrict__ Whi,
                                             const uint4* __restrict__ Wlo,
                                             const float* __restrict__ b) {
    constexpr int KB  = NIN / 32;
    constexpr int NT  = NOUT / 16;
    constexpr int NTW = NT / 4;
    const int t    = (int)threadIdx.x;
    const int wave = t >> 6;
    const int l15  = t & 15;
    const int quad = (t >> 4) & 3;

    floatx4 acc[NTW];
#pragma unroll
    for (int i = 0; i < NTW; ++i) acc[i] = (floatx4){0.f, 0.f, 0.f, 0.f};

#pragma unroll 2
    for (int kb = 0; kb < KB; ++kb) {
        Frag8 ahi, alo;
        const float* src = in_lds + l15 * STRIDE + kb * 32 + quad * 8;
        float4 f0 = *(const float4*)src;
        float4 f1 = *(const float4*)(src + 4);
        cvt_hi_lo(f0, f1, ahi, alo);
#pragma unroll
        for (int i = 0; i < NTW; ++i) {
            int widx = (kb * NT + wave * NTW + i) * 64 + (t & 63);
            Frag8 bhi, blo;
            *(uint4*)bhi.u = Whi[widx];
            *(uint4*)blo.u = Wlo[widx];
            acc[i] = __builtin_amdgcn_mfma_f32_16x16x32_bf16(alo.s, bhi.s, acc[i], 0, 0, 0);
            acc[i] = __builtin_amdgcn_mfma_f32_16x16x32_bf16(ahi.s, blo.s, acc[i], 0, 0, 0);
            acc[i] = __builtin_amdgcn_mfma_f32_16x16x32_bf16(ahi.s, bhi.s, acc[i], 0, 0, 0);
        }
    }
#pragma unroll
    for (int i = 0; i < NTW; ++i) {
        int n = (wave * NTW + i) * 16 + l15;
        float bias = b[n];
#pragma unroll
        for (int r = 0; r < 4; ++r) {
            float v = acc[i][r] + bias;
            if (RELU) v = fmaxf(v, 0.f);
            out_lds[(quad * 4 + r) * STRIDE + OOFF + n] = v;
        }
    }
}

// ---- edge message MLP (exact R5 structure): 32-edge tiles + atomic scatter
#define ETE 32
__global__ __launch_bounds__(256, 2)
void edge_mlp(const float* __restrict__ x, const int2* __restrict__ edges,
              const int* __restrict__ counter, int cap, float* __restrict__ aggr,
              const uint4* __restrict__ pack,
              const float* __restrict__ bm1, const float* __restrict__ bm2,
              const float* __restrict__ bm3) {
    __shared__ float bufA[ETE * STRIDE];
    __shared__ float bufB[ETE * STRIDE];
    __shared__ int sL[ETE], rL[ETE];
    const uint4* W1hi = pack + pk_off_hi(0);
    const uint4* W1lo = pack + pk_off_lo(0);
    const uint4* W2hi = pack + pk_off_hi(1);
    const uint4* W2lo = pack + pk_off_lo(1);
    const uint4* W3hi = pack + pk_off_hi(2);
    const uint4* W3lo = pack + pk_off_lo(2);
    const int count = min(counter[0], cap);
    const int ntiles = (count + ETE - 1) / ETE;
    const int t = (int)threadIdx.x;
    for (int tile = (int)blockIdx.x; tile < ntiles; tile += (int)gridDim.x) {
        const int base = tile * ETE;
        if (t < ETE) {
            int eg = base + t;
            int2 ed = (eg < count) ? edges[eg] : make_int2(0, -1);
            sL[t] = ed.x; rL[t] = ed.y;
        }
        __syncthreads();
        for (int idx = t; idx < ETE * 32; idx += 256) {
            int e = idx >> 5;
            int f4 = (idx & 31) * 4;
            int node = (f4 < 64) ? sL[e] : rL[e];
            float4 v = make_float4(0.f, 0.f, 0.f, 0.f);
            if (rL[e] >= 0) v = *(const float4*)(x + (size_t)node * 64 + (f4 & 63));
            *(float4*)(bufA + e * STRIDE + f4) = v;
        }
        __syncthreads();
        mfma_layer<128, 256, true >(bufA, bufB, W1hi, W1lo, bm1);
        __syncthreads();
        mfma_layer<256, 256, true >(bufB, bufA, W2hi, W2lo, bm2);
        __syncthreads();
        mfma_layer<256, 128, false>(bufA, bufB, W3hi, W3lo, bm3);
        __syncthreads();
        for (int idx = t; idx < ETE * 128; idx += 256) {
            int e = idx >> 7, o = idx & 127;
            if (base + e < count) {
                atomicAdd(&aggr[(size_t)rL[e] * 128 + o], bufB[e * STRIDE + o]);
            }
        }
        __syncthreads();
    }
}

// ---- fused node pipeline, MFMA (R5 style): 16 nodes/block, 64 blocks ------
__global__ __launch_bounds__(256, 1)
void node_update(const float* __restrict__ x, const float* __restrict__ actions,
                 const float* __restrict__ aggr, int n_agents,
                 const uint4* __restrict__ pack,
                 const float* __restrict__ ba1, const float* __restrict__ ba2,
                 const float* __restrict__ ba3,
                 const float* __restrict__ bu1, const float* __restrict__ bu2,
                 const float* __restrict__ bu3,
                 const float* __restrict__ Wact, const float* __restrict__ bact,
                 const float* __restrict__ bh1, const float* __restrict__ bh2,
                 const float* __restrict__ Wq,  const float* __restrict__ bq,
                 float* __restrict__ out) {
    __shared__ float bufA[16 * STRIDE];
    __shared__ float bufB[16 * STRIDE];
    __shared__ float qpart[16][17];
    const int t = (int)threadIdx.x;
    const int base = (int)blockIdx.x * 16;

    // stage aggr rows -> bufA[:, 0:128]
    for (int idx = t; idx < 16 * 32; idx += 256) {
        int e = idx >> 5, f4 = (idx & 31) * 4;
        float4 v = make_float4(0.f, 0.f, 0.f, 0.f);
        if (base + e < n_agents) v = *(const float4*)(aggr + (size_t)(base + e) * 128 + f4);
        *(float4*)(bufA + e * STRIDE + f4) = v;
    }
    __syncthreads();
    // agg MLP
    mfma_layer16<128, 128, true,  0 >(bufA, bufB, pack + pk_off_hi(3), pack + pk_off_lo(3), ba1);
    __syncthreads();
    mfma_layer16<128, 128, true,  0 >(bufB, bufA, pack + pk_off_hi(4), pack + pk_off_lo(4), ba2);
    __syncthreads();
    // a3 -> bufB[:, 64:192]; stage x -> bufB[:, 0:64]  (disjoint, same phase)
    mfma_layer16<128, 128, false, 64>(bufA, bufB, pack + pk_off_hi(5), pack + pk_off_lo(5), ba3);
    for (int idx = t; idx < 16 * 16; idx += 256) {
        int e = idx >> 4, f4 = (idx & 15) * 4;
        float4 v = make_float4(0.f, 0.f, 0.f, 0.f);
        if (base + e < n_agents) v = *(const float4*)(x + (size_t)(base + e) * 64 + f4);
        *(float4*)(bufB + e * STRIDE + f4) = v;
    }
    __syncthreads();
    // update MLP
    mfma_layer16<192, 256, true,  0 >(bufB, bufA, pack + pk_off_hi(6), pack + pk_off_lo(6), bu1);
    __syncthreads();
    mfma_layer16<256, 256, true,  0 >(bufA, bufB, pack + pk_off_hi(7), pack + pk_off_lo(7), bu2);
    __syncthreads();
    // u3 (feats) -> bufA[:, 0:128]; ap = relu(actions@Wact) -> bufA[:, 128:256]
    mfma_layer16<256, 128, false, 0 >(bufB, bufA, pack + pk_off_hi(8), pack + pk_off_lo(8), bu3);
    {
        int e = t >> 4, c0 = (t & 15) * 8;
        float accp[8];
#pragma unroll
        for (int c = 0; c < 8; ++c) accp[c] = bact[c0 + c];
        if (base + e < n_agents) {
#pragma unroll
            for (int k = 0; k < 16; ++k) {
                float av = actions[(size_t)(base + e) * 16 + k];
#pragma unroll
                for (int c = 0; c < 8; ++c)
                    accp[c] += av * Wact[(size_t)k * 128 + c0 + c];
            }
        }
#pragma unroll
        for (int c = 0; c < 8; ++c)
            bufA[e * STRIDE + 128 + c0 + c] = fmaxf(accp[c], 0.f);
    }
    __syncthreads();
    // head
    mfma_layer16<256, 256, true, 0>(bufA, bufB, pack + pk_off_hi(9),  pack + pk_off_lo(9),  bh1);
    __syncthreads();
    mfma_layer16<256, 256, true, 0>(bufB, bufA, pack + pk_off_hi(10), pack + pk_off_lo(10), bh2);
    __syncthreads();
    // q = z2 @ Wq + bq : 16 threads per node, 16 cols each
    {
        int e = t >> 4, g = t & 15;
        const float* z = bufA + e * STRIDE + g * 16;
        const float* w = Wq + g * 16;
        float p = 0.f;
#pragma unroll
        for (int j = 0; j < 16; j += 4) {
            float4 zv = *(const float4*)(z + j);
            float4 wv = *(const float4*)(w + j);
            p += zv.x * wv.x + zv.y * wv.y + zv.z * wv.z + zv.w * wv.w;
        }
        qpart[e][g] = p;
    }
    __syncthreads();
    if (t < 16 && base + t < n_agents) {
        float s = bq[0];
#pragma unroll
        for (int g = 0; g < 16; ++g) s += qpart[t][g];
        out[base + t] = s;
    }
}

extern "C" void kernel_launch(void* const* d_in, const int* in_sizes, int n_in,
                              void* d_out, int out_size, void* d_ws, size_t ws_size,
                              hipStream_t stream) {
    const float* x        = (const float*)d_in[0];
    const float* actions  = (const float*)d_in[1];
    const int*   senders  = (const int*)d_in[2];
    const int*   receivers= (const int*)d_in[3];
    const float* Wm1 = (const float*)d_in[5],  *bm1 = (const float*)d_in[6];
    const float* Wm2 = (const float*)d_in[7],  *bm2 = (const float*)d_in[8];
    const float* Wm3 = (const float*)d_in[9],  *bm3 = (const float*)d_in[10];
    const float* Wa1 = (const float*)d_in[11], *ba1 = (const float*)d_in[12];
    const float* Wa2 = (const float*)d_in[13], *ba2 = (const float*)d_in[14];
    const float* Wa3 = (const float*)d_in[15], *ba3 = (const float*)d_in[16];
    const float* Wu1 = (const float*)d_in[17], *bu1 = (const float*)d_in[18];
    const float* Wu2 = (const float*)d_in[19], *bu2 = (const float*)d_in[20];
    const float* Wu3 = (const float*)d_in[21], *bu3 = (const float*)d_in[22];
    const float* Wact= (const float*)d_in[23], *bact= (const float*)d_in[24];
    const float* Wh1 = (const float*)d_in[25], *bh1 = (const float*)d_in[26];
    const float* Wh2 = (const float*)d_in[27], *bh2 = (const float*)d_in[28];
    const float* Wq  = (const float*)d_in[29], *bq  = (const float*)d_in[30];

    const int E = in_sizes[2];
    const int n_agents = out_size;

    // ws: [0,4) counter | [1024, +512K) aggr | packed W | edges
    char* ws = (char*)d_ws;
    int*   counter = (int*)ws;
    float* aggr    = (float*)(ws + 1024);
    const size_t packOff = 1024 + (size_t)n_agents * 128 * sizeof(float);
    uint4* pack    = (uint4*)(ws + packOff);
    const size_t packBytes = (size_t)2 * PK_TOTAL * 16;
    const size_t edgeOff = packOff + packBytes;
    int2*  edges   = (int2*)(ws + edgeOff);
    int cap = (int)((ws_size > edgeOff) ? (ws_size - edgeOff) / sizeof(int2) : 0);
    if (cap > E) cap = E;

    hipMemsetAsync(ws, 0, packOff, stream);   // counter + aggr

    PackPtrs P;
    P.W[0] = Wm1; P.W[1] = Wm2; P.W[2] = Wm3;
    P.W[3] = Wa1; P.W[4] = Wa2; P.W[5] = Wa3;
    P.W[6] = Wu1; P.W[7] = Wu2; P.W[8] = Wu3;
    P.W[9] = Wh1; P.W[10] = Wh2;
    const int FB = (E + FILT_CHUNK - 1) / FILT_CHUNK;
    const int PB = (PK_TOTAL + 255) / 256;
    pack_and_filter<<<FB + PB, 256, 0, stream>>>(P, pack, senders, receivers,
                                                 E, n_agents, cap, counter,
                                                 edges, FB);

    edge_mlp<<<512, 256, 0, stream>>>(x, edges, counter, cap, aggr, pack,
                                      bm1, bm2, bm3);

    node_update<<<(n_agents + 15) / 16, 256, 0, stream>>>(
        x, actions, aggr, n_agents, pack,
        ba1, ba2, ba3, bu1, bu2, bu3, Wact, bact, bh1, bh2, Wq, bq,
        (float*)d_out);
}